// Round 1
// baseline (165.869 us; speedup 1.0000x reference)
//
#include <hip/hip_runtime.h>
#include <cmath>

namespace {
constexpr int kB  = 256;
constexpr int kK1 = 4097;   // NCE_K + 1
constexpr int kD  = 128;
constexpr float kInvT = 1.0f / 0.07f;
constexpr float kInvM = 1.0f / 4096.0f;
}

// ws layout (doubles): [0]=Q_t, [1..4]=Q_s[n], [5]=P_t, [6..9]=P_s[n]
__global__ void init_ws_kernel(double* __restrict__ ws) {
    int i = threadIdx.x;
    if (i < 10) ws[i] = 0.0;
}

__global__ __launch_bounds__(256) void mlcpc_main_kernel(
    const float* __restrict__ feats_s,
    const float* __restrict__ f_t,
    const int*   __restrict__ idx,
    const int*   __restrict__ cidx,
    const float* __restrict__ mem_s,
    const float* __restrict__ mem_t,
    double*      __restrict__ ws)
{
    __shared__ float4 shf[5][32];   // [0]=f_t[b], [1..4]=feats_s[n][b]
    __shared__ double sred[4][5];

    const int b   = blockIdx.x;
    const int tid = threadIdx.x;

    // Stage the 5 query vectors for this b (640 floats) into LDS.
    for (int i = tid; i < 160; i += 256) {
        const int which = i >> 5;
        const int off   = i & 31;
        const float* src = (which == 0)
            ? (f_t + (size_t)b * kD)
            : (feats_s + ((size_t)(which - 1) * kB + b) * kD);
        shf[which][off] = reinterpret_cast<const float4*>(src)[off];
    }
    __syncthreads();

    const int ql = tid & 3;                       // lane within quad
    const int gq = blockIdx.y * 64 + (tid >> 2);  // global quad id in [0,512)

    float aqt = 0.f, aq0 = 0.f, aq1 = 0.f, aq2 = 0.f, aq3 = 0.f;

    for (int k = gq; k < kK1; k += 512) {
        const int row = (k == 0) ? idx[b] : cidx[(size_t)b * kK1 + k];
        const float4* wsr = reinterpret_cast<const float4*>(mem_s + (size_t)row * kD);
        const float4* wtr = reinterpret_cast<const float4*>(mem_t + (size_t)row * kD);

        float dt = 0.f, d0 = 0.f, d1 = 0.f, d2 = 0.f, d3 = 0.f;
#pragma unroll
        for (int j = 0; j < 8; ++j) {
            const int e = ql + j * 4;             // quad covers contiguous 64B/instr
            const float4 a  = wsr[e];
            const float4 c  = wtr[e];
            const float4 ft = shf[0][e];
            const float4 g0 = shf[1][e];
            const float4 g1 = shf[2][e];
            const float4 g2 = shf[3][e];
            const float4 g3 = shf[4][e];
            dt += a.x * ft.x + a.y * ft.y + a.z * ft.z + a.w * ft.w;
            d0 += c.x * g0.x + c.y * g0.y + c.z * g0.z + c.w * g0.w;
            d1 += c.x * g1.x + c.y * g1.y + c.z * g1.z + c.w * g1.w;
            d2 += c.x * g2.x + c.y * g2.y + c.z * g2.z + c.w * g2.w;
            d3 += c.x * g3.x + c.y * g3.y + c.z * g3.z + c.w * g3.w;
        }
        // quad butterfly: all 4 lanes end with full 128-dot
#pragma unroll
        for (int off = 1; off <= 2; off <<= 1) {
            dt += __shfl_xor(dt, off);
            d0 += __shfl_xor(d0, off);
            d1 += __shfl_xor(d1, off);
            d2 += __shfl_xor(d2, off);
            d3 += __shfl_xor(d3, off);
        }
        if (ql == 0) {
            const float st = dt * kInvT;
            const float s0 = d0 * kInvT;
            const float s1 = d1 * kInvT;
            const float s2 = d2 * kInvT;
            const float s3 = d3 * kInvT;
            const float w  = (k == 0) ? kInvM : 1.0f;  // positive gets 1/m weight
            aqt += w * expf(st);
            aq0 += w * expf(s0);
            aq1 += w * expf(s1);
            aq2 += w * expf(s2);
            aq3 += w * expf(s3);
            if (k == 0) {  // positive-sample logit sums (once per b)
                atomicAdd(&ws[5], (double)st);
                atomicAdd(&ws[6], (double)s0);
                atomicAdd(&ws[7], (double)s1);
                atomicAdd(&ws[8], (double)s2);
                atomicAdd(&ws[9], (double)s3);
            }
        }
    }

    // wave-level tree reduce (non-ql0 lanes hold zeros)
#pragma unroll
    for (int off = 32; off >= 1; off >>= 1) {
        aqt += __shfl_down(aqt, off);
        aq0 += __shfl_down(aq0, off);
        aq1 += __shfl_down(aq1, off);
        aq2 += __shfl_down(aq2, off);
        aq3 += __shfl_down(aq3, off);
    }
    const int lane = tid & 63;
    const int wid  = tid >> 6;
    if (lane == 0) {
        sred[wid][0] = (double)aqt;
        sred[wid][1] = (double)aq0;
        sred[wid][2] = (double)aq1;
        sred[wid][3] = (double)aq2;
        sred[wid][4] = (double)aq3;
    }
    __syncthreads();
    if (tid < 5) {
        const double s = sred[0][tid] + sred[1][tid] + sred[2][tid] + sred[3][tid];
        atomicAdd(&ws[tid], s);
    }
}

__global__ void finalize_kernel(const double* __restrict__ ws, float* __restrict__ out) {
    if (threadIdx.x == 0 && blockIdx.x == 0) {
        const double invB = 1.0 / 256.0;
        double loss_t = 4.0 * (-(ws[5] * invB) + log(ws[0] * invB));
        double loss_s = 0.0;
        for (int n = 0; n < 4; ++n)
            loss_s += -(ws[6 + n] * invB) + log(ws[1 + n] * invB);
        out[0] = (float)(loss_s + loss_t);
    }
}

extern "C" void kernel_launch(void* const* d_in, const int* in_sizes, int n_in,
                              void* d_out, int out_size, void* d_ws, size_t ws_size,
                              hipStream_t stream) {
    const float* feats_s = (const float*)d_in[0];
    const float* f_t     = (const float*)d_in[1];
    const int*   idx     = (const int*)d_in[2];
    const int*   cidx    = (const int*)d_in[3];
    const float* mem_s   = (const float*)d_in[4];
    const float* mem_t   = (const float*)d_in[5];
    double* ws  = (double*)d_ws;
    float*  out = (float*)d_out;

    init_ws_kernel<<<1, 64, 0, stream>>>(ws);
    dim3 grid(kB, 8);
    mlcpc_main_kernel<<<grid, 256, 0, stream>>>(feats_s, f_t, idx, cidx,
                                                mem_s, mem_t, ws);
    finalize_kernel<<<1, 64, 0, stream>>>(ws, out);
}